// Round 2
// 254.969 us; speedup vs baseline: 1.6744x; 1.6744x over previous
//
#include <hip/hip_runtime.h>
#include <hip/hip_bf16.h>

typedef __hip_bfloat16 bf16;
typedef __attribute__((ext_vector_type(8))) short short8;   // 8 bf16, 4 VGPRs
typedef __attribute__((ext_vector_type(4))) short shortx4;  // 4 bf16 (HIP owns "short4")
typedef __attribute__((ext_vector_type(4))) float floatx4;  // MFMA acc

// B=8, T=8192, D=64, M=256, chunk L=64, NCHUNK=1024, NTOK=65536
#define NEED_WS_BYTES 110625024ULL

__device__ __forceinline__ float b2f(bf16 x) { return __bfloat162float(x); }
__device__ __forceinline__ bf16  f2b(float x) { return __float2bfloat16(x); }
__device__ __forceinline__ float bflo(unsigned u) { return __uint_as_float(u << 16); }
__device__ __forceinline__ float bfhi(unsigned u) { return __uint_as_float(u & 0xffff0000u); }

// dtype-dispatched input load: isf32 ? f32 : bf16
__device__ __forceinline__ float ldin(const void* p, size_t i, int isf32) {
  return isf32 ? ((const float*)p)[i] : b2f(((const bf16*)p)[i]);
}

// ---- k_detect: decide whether inputs are f32 or bf16 -----------------------
__global__ __launch_bounds__(256) void k_detect(const void* __restrict__ q,
                                                int* __restrict__ flag) {
  __shared__ int cnt;
  if (threadIdx.x == 0) cnt = 0;
  __syncthreads();
  const unsigned short* u = (const unsigned short*)q;
  int c = 0;
  for (int e = threadIdx.x; e < 2048; e += 256) {
    unsigned short w = u[2 * e];
    int ex = (w >> 7) & 0xFF;
    if ((w & 0x7FFF) != 0 && (ex < 110 || ex > 140)) c++;
  }
  atomicAdd(&cnt, c);
  __syncthreads();
  if (threadIdx.x == 0) *flag = (cnt > 512) ? 1 : 0;
}

// ---- k_omega: convert omega -> bf16 copy (R11: bf16-omega exact enough) ----
__global__ __launch_bounds__(256) void k_omega(const void* __restrict__ omega,
                                               bf16* __restrict__ omb,
                                               const int* __restrict__ flag) {
  int isf32 = *flag;
  int e = blockIdx.x * 256 + threadIdx.x;
  omb[e] = f2b(ldin(omega, e, isf32));
}

// ---- k_phi (MFMA): dot = x@omega^T via mfma_f32_16x16x32_bf16 --------------
// (-0.5||x||^2 cancels exactly under the rowmax subtraction; omitted.)
// grid (1024, 2) x 256 (4 waves): wave w -> tokens m0=w*16, all 256 features.
// Layouts (m89/m91-verified): A[m=lane&15][k=quad*8+j], B[n=lane&15][k=quad*8+j],
// C: col=lane&15, row=quad*4+reg.
// SPILL LESSON (R5-R11): amdgpu_waves_per_eu max>2 => allocator demotes big
// arrays to scratch. Tripwire: k_phi FETCH > 200 MB = spill = revert.
__global__ __launch_bounds__(256)
__attribute__((amdgpu_waves_per_eu(1, 2))) void k_phi(
    const void* __restrict__ q, const void* __restrict__ k,
    const bf16* __restrict__ omb, bf16* __restrict__ phiQ,
    bf16* __restrict__ phiK, const int* __restrict__ flag) {
  __shared__ short xb[64 * 72];   // x*0.125 bf16, row stride 72 (144 B, 16B-aligned)
  int isf32 = *flag;
  int tid = threadIdx.x;
  int isK = blockIdx.y;
  const void* src = isK ? k : q;
  bf16* dst = isK ? phiK : phiQ;
  size_t tok0 = (size_t)blockIdx.x * 64;

  for (int e = tid; e < 4096; e += 256) {
    int t = e >> 6, d = e & 63;
    bf16 h = f2b(ldin(src, tok0 * 64 + e, isf32) * 0.125f);
    xb[t * 72 + d] = *reinterpret_cast<short*>(&h);
  }
  __syncthreads();

  int li = tid & 15;
  int quad = (tid >> 4) & 3;
  int m0 = (tid >> 6) * 16;

  short8 a0 = *reinterpret_cast<const short8*>(&xb[(m0 + li) * 72 + quad * 8]);
  short8 a1 = *reinterpret_cast<const short8*>(&xb[(m0 + li) * 72 + 32 + quad * 8]);

  floatx4 c[16];
  #pragma unroll
  for (int n0 = 0; n0 < 16; ++n0) {
    const short* bp = (const short*)omb + (size_t)(n0 * 16 + li) * 64 + quad * 8;
    short8 b0 = *reinterpret_cast<const short8*>(bp);
    short8 b1 = *reinterpret_cast<const short8*>(bp + 32);
    floatx4 acc = {0.f, 0.f, 0.f, 0.f};
    acc = __builtin_amdgcn_mfma_f32_16x16x32_bf16(a0, b0, acc, 0, 0, 0);
    acc = __builtin_amdgcn_mfma_f32_16x16x32_bf16(a1, b1, acc, 0, 0, 0);
    c[n0] = acc;
  }

  float mx[4];
  #pragma unroll
  for (int r = 0; r < 4; ++r) {
    float m = c[0][r];
    #pragma unroll
    for (int n0 = 1; n0 < 16; ++n0) m = fmaxf(m, c[n0][r]);
    mx[r] = m;
  }
  #pragma unroll
  for (int mask = 1; mask < 16; mask <<= 1) {
    #pragma unroll
    for (int r = 0; r < 4; ++r) mx[r] = fmaxf(mx[r], __shfl_xor(mx[r], mask, 64));
  }

  #pragma unroll
  for (int r = 0; r < 4; ++r) {
    size_t n = tok0 + m0 + quad * 4 + r;
    bf16* drow = dst + n * 256 + li;
    #pragma unroll
    for (int n0 = 0; n0 < 16; ++n0)
      drow[n0 * 16] = f2b(__expf(c[n0][r] - mx[r]) * 0.0625f);  // 1/sqrt(256)
  }
}

// ---- k_slocal: per-chunk S^T (d x i, TRANSPOSED) bf16 and z f32 ------------
// SlocT[chunk][d][i] = sum_t phiK[t][i] * V[t][d].  Transposed layout:
//  (a) stores coalesced (lanes i consecutive per jj), was stride-128B scatter
//  (b) k_out stages SpT rows directly as MFMA b-fragments (straight copy)
// k_sprefix is elementwise over the chunk axis -> layout-agnostic, unchanged.
__global__ __launch_bounds__(256) void k_slocal(
    const bf16* __restrict__ phiK, const void* __restrict__ v,
    bf16* __restrict__ SlocT, float* __restrict__ zloc,
    const int* __restrict__ flag) {
  __shared__ float vs[64 * 64];
  int isf32 = *flag;
  int chunk = blockIdx.x;
  size_t tok0 = (size_t)chunk * 64;
  int tid = threadIdx.x;
  for (int e = tid; e < 4096; e += 256) vs[e] = ldin(v, tok0 * 64 + e, isf32);
  __syncthreads();
  int i = tid;
  float acc[64];
  #pragma unroll
  for (int jj = 0; jj < 64; ++jj) acc[jj] = 0.f;
  float az = 0.f;
  #pragma unroll 2
  for (int t = 0; t < 64; ++t) {
    float pk = b2f(phiK[(tok0 + t) * 256 + i]);
    az += pk;
    const float* vr = vs + t * 64;
    #pragma unroll
    for (int jj = 0; jj < 64; ++jj) acc[jj] += pk * vr[jj];
  }
  bf16* Sb = SlocT + (size_t)chunk * 16384 + i;
  #pragma unroll
  for (int jj = 0; jj < 64; ++jj) Sb[(size_t)jj * 256] = f2b(acc[jj]);
  zloc[(size_t)chunk * 256 + i] = az;
}

// ---- k_sprefix: in-place exclusive prefix of SlocT over chunks (bf16) ------
// Elementwise over the 16384 elems/chunk -> independent of inner [d][i] layout.
__global__ __launch_bounds__(64) void k_sprefix(bf16* __restrict__ SlocT) {
  int b = blockIdx.x >> 8, i = blockIdx.x & 255;
  int d = threadIdx.x;
  size_t base = (size_t)b * 2097152 + (size_t)i * 64 + d;
  float vbuf[128];
  #pragma unroll
  for (int c = 0; c < 128; ++c) vbuf[c] = b2f(SlocT[base + (size_t)c * 16384]);
  float run = 0.f;
  #pragma unroll
  for (int c = 0; c < 128; ++c) { float t = vbuf[c]; vbuf[c] = run; run += t; }
  #pragma unroll
  for (int c = 0; c < 128; ++c) SlocT[base + (size_t)c * 16384] = f2b(vbuf[c]);
}

// ---- k_zprefix: in-place exclusive prefix of zloc over chunks (f32) --------
__global__ __launch_bounds__(64) void k_zprefix(float* __restrict__ zloc) {
  int b = blockIdx.x >> 2, ig = blockIdx.x & 3;
  int i = ig * 64 + threadIdx.x;
  size_t base = (size_t)b * 32768 + i;
  float vbuf[128];
  #pragma unroll
  for (int c = 0; c < 128; ++c) vbuf[c] = zloc[base + (size_t)c * 256];
  float run = 0.f;
  #pragma unroll
  for (int c = 0; c < 128; ++c) { float t = vbuf[c]; vbuf[c] = run; run += t; }
  #pragma unroll
  for (int c = 0; c < 128; ++c) zloc[base + (size_t)c * 256] = vbuf[c];
}

// ---- k_out (MFMA, replaces k_outA + k_outB): -------------------------------
// out[t] = (phiQ @ Sp + tril(A) @ V) / (phiQ.zp + rowsum(tril A) + eps)
// 1024 blocks x 4 waves; wave w owns m-tile (rows m0=w*16 .. +15).
//   mm1: A = phiQ @ phiK^T (K=256), triangular: only n0 <= w tiles computed.
//        Masked in-register; rowsum den-partials; bf16 A -> wave-private LDS.
//   mm2: out1 = phiQ @ Sp   (K=256), b-frags = SpT LDS rows (Sp transposed).
//   mm3: out2 = trilA @ V   (K=64),  V split hi+lo bf16 (keeps V f32-accurate;
//        the old VALU path used f32 V) -> 2 extra MFMA/tile, negligible.
// a1-frags (phiQ) loaded once, shared across mm1+mm2.
// LDS rows padded to odd-16B multiples (264/72 shorts): 4-bank row step,
// 16 rows/quad -> ~2-way on ds_read_b128 (free, G4).
// LDS total 61440 B -> 2 blocks/CU; waves_per_eu(1,2) (spill tripwire R5-R11).
__global__ __launch_bounds__(256)
__attribute__((amdgpu_waves_per_eu(1, 2))) void k_out(
    const bf16* __restrict__ phiQ, const bf16* __restrict__ phiK,
    const void* __restrict__ v, const bf16* __restrict__ SlocT,
    const float* __restrict__ zloc, void* __restrict__ outp,
    const int* __restrict__ flag) {
  __shared__ short spT[64 * 264];   // SpT[d][i], pad 8     33792 B
  __shared__ short vTh[64 * 72];    // V^T hi bf16           9216 B
  __shared__ short vTl[64 * 72];    // V^T lo bf16           9216 B
  __shared__ short aT[64 * 72];     // masked A[t][tau]      9216 B

  int isf32 = *flag;
  int chunk = blockIdx.x;
  size_t tok0 = (size_t)chunk * 64;
  int tid = threadIdx.x;
  int lane = tid & 63;
  int li = lane & 15;
  int quad = lane >> 4;
  int w = __builtin_amdgcn_readfirstlane(tid >> 6);  // wave id = m-tile
  int m0 = w * 16;

  // ---- stage SpT: straight 16B copy of this chunk's exclusive-prefix S^T ---
  {
    const short* src = (const short*)SlocT + (size_t)chunk * 16384;
    #pragma unroll
    for (int it = 0; it < 8; ++it) {
      int e = it * 256 + tid;
      int d = e >> 5, seg = e & 31;
      *reinterpret_cast<short8*>(&spT[d * 264 + seg * 8]) =
          *reinterpret_cast<const short8*>(src + d * 256 + seg * 8);
    }
  }
  // ---- stage V^T split hi/lo (coalesced f32 reads; lo==0 for bf16 input) ---
  #pragma unroll
  for (int it = 0; it < 16; ++it) {
    int e = it * 256 + tid;
    int tau = e >> 6, d = e & 63;
    float vv = ldin(v, tok0 * 64 + e, isf32);
    bf16 h = f2b(vv);
    bf16 l = f2b(vv - b2f(h));
    vTh[d * 72 + tau] = *reinterpret_cast<short*>(&h);
    vTl[d * 72 + tau] = *reinterpret_cast<short*>(&l);
  }
  // ---- zero own above-diagonal A region (rows wave-private: no race) -------
  {
    shortx4 z4 = {0, 0, 0, 0};
    int row = m0 + li;
    for (int c = (w + 1) * 16 + quad * 4; c < 64; c += 16)
      *reinterpret_cast<shortx4*>(&aT[row * 72 + c]) = z4;
  }

  // ---- a1-frags: phiQ rows of this m-tile (L2-hot; reused mm1+mm2) ---------
  const short* pqf = (const short*)phiQ + (tok0 + m0 + li) * 256 + quad * 8;
  short8 a1[8];
  #pragma unroll
  for (int kk = 0; kk < 8; ++kk)
    a1[kk] = *reinterpret_cast<const short8*>(pqf + kk * 32);

  // ---- mm1: A tiles, n0 <= w only (tiles above diagonal are all-masked) ----
  floatx4 c1[4];
  #pragma unroll
  for (int n0 = 0; n0 < 4; ++n0) c1[n0] = (floatx4){0.f, 0.f, 0.f, 0.f};
  const short* pkb = (const short*)phiK + tok0 * 256;
  #pragma unroll
  for (int n0 = 0; n0 < 4; ++n0) {
    if (n0 <= w) {
      const short* bp = pkb + (size_t)(n0 * 16 + li) * 256 + quad * 8;
      floatx4 acc = c1[n0];
      #pragma unroll
      for (int kk = 0; kk < 8; ++kk) {
        short8 b = *reinterpret_cast<const short8*>(bp + kk * 32);
        acc = __builtin_amdgcn_mfma_f32_16x16x32_bf16(a1[kk], b, acc, 0, 0, 0);
      }
      c1[n0] = acc;
    }
  }

  // ---- tril mask + den rowsum partials + write bf16 A to own LDS rows ------
  float dpart[4] = {0.f, 0.f, 0.f, 0.f};
  #pragma unroll
  for (int n0 = 0; n0 < 4; ++n0) {
    if (n0 <= w) {
      int tau = n0 * 16 + li;
      #pragma unroll
      for (int r = 0; r < 4; ++r) {
        int t = m0 + quad * 4 + r;
        float val = (tau <= t) ? c1[n0][r] : 0.f;
        dpart[r] += val;
        bf16 hh = f2b(val);
        aT[t * 72 + tau] = *reinterpret_cast<short*>(&hh);
      }
    }
  }

  __syncthreads();   // spT/vTh/vTl ready (aT is wave-private: own rows only)

  // ---- mm2 (phiQ @ Sp) + mm3 (trilA @ Vhi + trilA @ Vlo), shared acc -------
  floatx4 o[4];
  #pragma unroll
  for (int n0 = 0; n0 < 4; ++n0) o[n0] = (floatx4){0.f, 0.f, 0.f, 0.f};

  const short* arow = &aT[(m0 + li) * 72 + quad * 8];
  short8 a3_0 = *reinterpret_cast<const short8*>(arow);
  short8 a3_1 = *reinterpret_cast<const short8*>(arow + 32);

  #pragma unroll
  for (int n0 = 0; n0 < 4; ++n0) {
    floatx4 acc = o[n0];
    const short* sp = &spT[(n0 * 16 + li) * 264 + quad * 8];
    #pragma unroll
    for (int kk = 0; kk < 8; ++kk) {
      short8 b = *reinterpret_cast<const short8*>(sp + kk * 32);
      acc = __builtin_amdgcn_mfma_f32_16x16x32_bf16(a1[kk], b, acc, 0, 0, 0);
    }
    const short* vph = &vTh[(n0 * 16 + li) * 72 + quad * 8];
    const short* vpl = &vTl[(n0 * 16 + li) * 72 + quad * 8];
    short8 bh0 = *reinterpret_cast<const short8*>(vph);
    short8 bh1 = *reinterpret_cast<const short8*>(vph + 32);
    short8 bl0 = *reinterpret_cast<const short8*>(vpl);
    short8 bl1 = *reinterpret_cast<const short8*>(vpl + 32);
    acc = __builtin_amdgcn_mfma_f32_16x16x32_bf16(a3_0, bh0, acc, 0, 0, 0);
    acc = __builtin_amdgcn_mfma_f32_16x16x32_bf16(a3_1, bh1, acc, 0, 0, 0);
    acc = __builtin_amdgcn_mfma_f32_16x16x32_bf16(a3_0, bl0, acc, 0, 0, 0);
    acc = __builtin_amdgcn_mfma_f32_16x16x32_bf16(a3_1, bl1, acc, 0, 0, 0);
    o[n0] = acc;
  }

  // ---- den: dpart += pq . zp  (lane li covers i in [li*16, li*16+16)) ------
  {
    const floatx4* zp4 =
        reinterpret_cast<const floatx4*>(zloc + (size_t)chunk * 256 + li * 16);
    floatx4 z0 = zp4[0], z1 = zp4[1], z2 = zp4[2], z3 = zp4[3];
    #pragma unroll
    for (int r = 0; r < 4; ++r) {
      const short* pqr =
          (const short*)phiQ + (tok0 + m0 + quad * 4 + r) * 256 + li * 16;
      short8 p0 = *reinterpret_cast<const short8*>(pqr);
      short8 p1 = *reinterpret_cast<const short8*>(pqr + 8);
      float s = dpart[r];
      #pragma unroll
      for (int j = 0; j < 4; ++j) s += bflo((unsigned short)p0[j]) * z0[j];
      #pragma unroll
      for (int j = 0; j < 4; ++j) s += bflo((unsigned short)p0[4 + j]) * z1[j];
      #pragma unroll
      for (int j = 0; j < 4; ++j) s += bflo((unsigned short)p1[j]) * z2[j];
      #pragma unroll
      for (int j = 0; j < 4; ++j) s += bflo((unsigned short)p1[4 + j]) * z3[j];
      dpart[r] = s;
    }
  }
  // butterfly over the quad's 16 lanes: every lane gets full den for its rows
  #pragma unroll
  for (int mask = 1; mask < 16; mask <<= 1) {
    #pragma unroll
    for (int r = 0; r < 4; ++r) dpart[r] += __shfl_xor(dpart[r], mask, 64);
  }

  // ---- epilogue: out[t][d] = (out1+out2) / (den + eps) ---------------------
  #pragma unroll
  for (int r = 0; r < 4; ++r) {
    float rd = 1.f / (dpart[r] + 1e-6f);
    size_t ob = (tok0 + m0 + quad * 4 + r) * 64 + li;
    if (isf32) {
      float* op = (float*)outp + ob;
      #pragma unroll
      for (int n0 = 0; n0 < 4; ++n0) op[n0 * 16] = o[n0][r] * rd;
    } else {
      bf16* op = (bf16*)outp + ob;
      #pragma unroll
      for (int n0 = 0; n0 < 4; ++n0) op[n0 * 16] = f2b(o[n0][r] * rd);
    }
  }
}

extern "C" void kernel_launch(void* const* d_in, const int* in_sizes, int n_in,
                              void* d_out, int out_size, void* d_ws, size_t ws_size,
                              hipStream_t stream) {
  (void)in_sizes; (void)n_in; (void)out_size;
  if (ws_size < NEED_WS_BYTES) return;   // diagnostic guard (absmax==3.859375)

  const void* q = d_in[0];
  const void* k = d_in[1];
  const void* v = d_in[2];
  const void* omega = d_in[3];

  int*   flag = (int*)d_ws;
  float* wsf  = (float*)d_ws + 64;       // data starts 256 B in
  bf16*  omb  = (bf16*)wsf;              // 16384 bf16
  float* zloc = wsf + 131072;            // 1024*256 f32
  bf16*  Sloc = (bf16*)(wsf + 393216);   // 1024*256*64 bf16 (TRANSPOSED [d][i])
  bf16*  phiQ = (bf16*)(wsf + 8781824);  // 65536*256 bf16
  bf16*  phiK = (bf16*)(wsf + 17170432); // 65536*256 bf16
  // ATg region (wsf + 25559040) no longer used: A stays in LDS inside k_out.

  k_detect<<<1, 256, 0, stream>>>(q, flag);
  k_omega<<<64, 256, 0, stream>>>(omega, omb, flag);
  k_phi<<<dim3(1024, 2), 256, 0, stream>>>(q, k, omb, phiQ, phiK, flag);
  k_slocal<<<1024, 256, 0, stream>>>(phiK, v, Sloc, zloc, flag);
  k_sprefix<<<2048, 64, 0, stream>>>(Sloc);
  k_zprefix<<<32, 64, 0, stream>>>(zloc);
  k_out<<<1024, 256, 0, stream>>>(phiQ, phiK, v, Sloc, zloc, d_out, flag);
}

// Round 3
// 232.130 us; speedup vs baseline: 1.8392x; 1.0984x over previous
//
#include <hip/hip_runtime.h>
#include <hip/hip_bf16.h>

typedef __hip_bfloat16 bf16;
typedef __attribute__((ext_vector_type(8))) short short8;   // 8 bf16, 4 VGPRs
typedef __attribute__((ext_vector_type(4))) short shortx4;  // 4 bf16 (HIP owns "short4")
typedef __attribute__((ext_vector_type(4))) float floatx4;  // MFMA acc

// B=8, T=8192, D=64, M=256, chunk L=64, NCHUNK=1024, NTOK=65536
#define NEED_WS_BYTES 110625024ULL

__device__ __forceinline__ float b2f(bf16 x) { return __bfloat162float(x); }
__device__ __forceinline__ bf16  f2b(float x) { return __float2bfloat16(x); }
__device__ __forceinline__ float bflo(unsigned u) { return __uint_as_float(u << 16); }
__device__ __forceinline__ float bfhi(unsigned u) { return __uint_as_float(u & 0xffff0000u); }

// dtype-dispatched input load: isf32 ? f32 : bf16
__device__ __forceinline__ float ldin(const void* p, size_t i, int isf32) {
  return isf32 ? ((const float*)p)[i] : b2f(((const bf16*)p)[i]);
}

// f32 -> bf16 bits of (f * 0.125)  (0.125 = 1/sqrt(64), exact exponent shift)
__device__ __forceinline__ short sb(float f) {
  bf16 h = f2b(f * 0.125f);
  return *reinterpret_cast<short*>(&h);
}
// bf16 bits -> bf16 bits of (x * 0.125) (exact: exponent-3; f2b of exact value = id)
__device__ __forceinline__ short scale_b(short u) {
  float f = __uint_as_float(((unsigned)(unsigned short)u) << 16) * 0.125f;
  bf16 h = f2b(f);
  return *reinterpret_cast<short*>(&h);
}

// ---- k_detect: decide whether inputs are f32 or bf16 -----------------------
__global__ __launch_bounds__(256) void k_detect(const void* __restrict__ q,
                                                int* __restrict__ flag) {
  __shared__ int cnt;
  if (threadIdx.x == 0) cnt = 0;
  __syncthreads();
  const unsigned short* u = (const unsigned short*)q;
  int c = 0;
  for (int e = threadIdx.x; e < 2048; e += 256) {
    unsigned short w = u[2 * e];
    int ex = (w >> 7) & 0xFF;
    if ((w & 0x7FFF) != 0 && (ex < 110 || ex > 140)) c++;
  }
  atomicAdd(&cnt, c);
  __syncthreads();
  if (threadIdx.x == 0) *flag = (cnt > 512) ? 1 : 0;
}

// ---- k_omega: convert omega -> bf16 copy (R11: bf16-omega exact enough) ----
__global__ __launch_bounds__(256) void k_omega(const void* __restrict__ omega,
                                               bf16* __restrict__ omb,
                                               const int* __restrict__ flag) {
  int isf32 = *flag;
  int e = blockIdx.x * 256 + threadIdx.x;
  omb[e] = f2b(ldin(omega, e, isf32));
}

// ---- k_phi (MFMA): dot = x@omega^T via mfma_f32_16x16x32_bf16 --------------
// (-0.5||x||^2 cancels exactly under the rowmax subtraction; omitted.)
// R2 rewrite: (a) NO x-staging LDS / no barrier — each x element feeds exactly
// one lane's a-frag (zero reuse), so load a-frags straight from global (L3-hot,
// 16B/lane). (b) Output through wave-private LDS tile -> coalesced 16B stores
// (was 2B scatter). (c) waves_per_eu(1,4): 88 VGPR < 128 so no spill risk
// (R5-R11 lesson applied at (1,2) was for >128-reg live sets); LDS 33.8 KB
// -> 4 blocks/CU -> 16 waves/CU (50%) vs 19.6% before.
// Layouts (m89/m91-verified): A[m=lane&15][k=quad*8+j], B[n=lane&15][k=quad*8+j],
// C: col=lane&15, row=quad*4+reg.
// Tripwire: k_phi FETCH > 200 MB = spill = revert waves_per_eu.
__global__ __launch_bounds__(256)
__attribute__((amdgpu_waves_per_eu(1, 4))) void k_phi(
    const void* __restrict__ q, const void* __restrict__ k,
    const bf16* __restrict__ omb, bf16* __restrict__ phiQ,
    bf16* __restrict__ phiK, const int* __restrict__ flag) {
  __shared__ short ob[4][16][264];   // per-wave out tile, 528B row (16B-mult)
  int isf32 = *flag;
  int tid = threadIdx.x;
  int isK = blockIdx.y;
  const void* src = isK ? k : q;
  bf16* dst = isK ? phiK : phiQ;
  size_t tok0 = (size_t)blockIdx.x * 64;

  int li = tid & 15;
  int quad = (tid >> 4) & 3;
  int w = tid >> 6;               // wave id -> token block m0
  int m0 = w * 16;
  size_t row = tok0 + m0 + li;    // this lane's token row

  // ---- a-frags straight from global (scaled f32/bf16 -> bf16 in regs) ------
  short8 a0, a1;
  if (isf32) {
    const float* xr = (const float*)src + row * 64;
    float4 f0 = *reinterpret_cast<const float4*>(xr + quad * 8);
    float4 f1 = *reinterpret_cast<const float4*>(xr + quad * 8 + 4);
    float4 f2 = *reinterpret_cast<const float4*>(xr + 32 + quad * 8);
    float4 f3 = *reinterpret_cast<const float4*>(xr + 32 + quad * 8 + 4);
    a0[0] = sb(f0.x); a0[1] = sb(f0.y); a0[2] = sb(f0.z); a0[3] = sb(f0.w);
    a0[4] = sb(f1.x); a0[5] = sb(f1.y); a0[6] = sb(f1.z); a0[7] = sb(f1.w);
    a1[0] = sb(f2.x); a1[1] = sb(f2.y); a1[2] = sb(f2.z); a1[3] = sb(f2.w);
    a1[4] = sb(f3.x); a1[5] = sb(f3.y); a1[6] = sb(f3.z); a1[7] = sb(f3.w);
  } else {
    const short* xr = (const short*)src + row * 64;
    short8 r0 = *reinterpret_cast<const short8*>(xr + quad * 8);
    short8 r1 = *reinterpret_cast<const short8*>(xr + 32 + quad * 8);
    #pragma unroll
    for (int j = 0; j < 8; ++j) { a0[j] = scale_b(r0[j]); a1[j] = scale_b(r1[j]); }
  }

  // ---- 16 n0-tiles x 2 K-halves = 32 MFMA; omega rows from L2 --------------
  floatx4 c[16];
  #pragma unroll
  for (int n0 = 0; n0 < 16; ++n0) {
    const short* bp = (const short*)omb + (size_t)(n0 * 16 + li) * 64 + quad * 8;
    short8 b0 = *reinterpret_cast<const short8*>(bp);
    short8 b1 = *reinterpret_cast<const short8*>(bp + 32);
    floatx4 acc = {0.f, 0.f, 0.f, 0.f};
    acc = __builtin_amdgcn_mfma_f32_16x16x32_bf16(a0, b0, acc, 0, 0, 0);
    acc = __builtin_amdgcn_mfma_f32_16x16x32_bf16(a1, b1, acc, 0, 0, 0);
    c[n0] = acc;
  }

  // ---- rowmax over 256 features: 16-tile local max + 16-lane butterfly -----
  float mx[4];
  #pragma unroll
  for (int r = 0; r < 4; ++r) {
    float m = c[0][r];
    #pragma unroll
    for (int n0 = 1; n0 < 16; ++n0) m = fmaxf(m, c[n0][r]);
    mx[r] = m;
  }
  #pragma unroll
  for (int mask = 1; mask < 16; mask <<= 1) {
    #pragma unroll
    for (int r = 0; r < 4; ++r) mx[r] = fmaxf(mx[r], __shfl_xor(mx[r], mask, 64));
  }

  // ---- exp -> wave-private LDS tile (no barrier: same wave reads it) -------
  #pragma unroll
  for (int r = 0; r < 4; ++r) {
    #pragma unroll
    for (int n0 = 0; n0 < 16; ++n0) {
      bf16 h = f2b(__expf(c[n0][r] - mx[r]) * 0.0625f);  // 1/sqrt(256)
      ob[w][quad * 4 + r][n0 * 16 + li] = *reinterpret_cast<short*>(&h);
    }
  }

  // ---- coalesced store: lane (quad,li) -> row li, 16B chunk (it*4+quad) ----
  size_t srow = tok0 + m0 + li;
  #pragma unroll
  for (int it = 0; it < 8; ++it) {
    int ch = it * 4 + quad;
    short8 vv = *reinterpret_cast<const short8*>(&ob[w][li][ch * 8]);
    *reinterpret_cast<short8*>((short*)dst + srow * 256 + ch * 8) = vv;
  }
}

// ---- k_slocal: per-chunk S^T (d x i, TRANSPOSED) bf16 and z f32 ------------
// SlocT[chunk][d][i] = sum_t phiK[t][i] * V[t][d].  Transposed layout:
//  (a) stores coalesced (lanes i consecutive per jj)
//  (b) k_out stages SpT rows directly as MFMA b-fragments (straight copy)
__global__ __launch_bounds__(256) void k_slocal(
    const bf16* __restrict__ phiK, const void* __restrict__ v,
    bf16* __restrict__ SlocT, float* __restrict__ zloc,
    const int* __restrict__ flag) {
  __shared__ float vs[64 * 64];
  int isf32 = *flag;
  int chunk = blockIdx.x;
  size_t tok0 = (size_t)chunk * 64;
  int tid = threadIdx.x;
  for (int e = tid; e < 4096; e += 256) vs[e] = ldin(v, tok0 * 64 + e, isf32);
  __syncthreads();
  int i = tid;
  float acc[64];
  #pragma unroll
  for (int jj = 0; jj < 64; ++jj) acc[jj] = 0.f;
  float az = 0.f;
  #pragma unroll 2
  for (int t = 0; t < 64; ++t) {
    float pk = b2f(phiK[(tok0 + t) * 256 + i]);
    az += pk;
    const float* vr = vs + t * 64;
    #pragma unroll
    for (int jj = 0; jj < 64; ++jj) acc[jj] += pk * vr[jj];
  }
  bf16* Sb = SlocT + (size_t)chunk * 16384 + i;
  #pragma unroll
  for (int jj = 0; jj < 64; ++jj) Sb[(size_t)jj * 256] = f2b(acc[jj]);
  zloc[(size_t)chunk * 256 + i] = az;
}

// ---- k_sprefix: in-place exclusive prefix of SlocT over chunks (bf16) ------
__global__ __launch_bounds__(64) void k_sprefix(bf16* __restrict__ SlocT) {
  int b = blockIdx.x >> 8, i = blockIdx.x & 255;
  int d = threadIdx.x;
  size_t base = (size_t)b * 2097152 + (size_t)i * 64 + d;
  float vbuf[128];
  #pragma unroll
  for (int c = 0; c < 128; ++c) vbuf[c] = b2f(SlocT[base + (size_t)c * 16384]);
  float run = 0.f;
  #pragma unroll
  for (int c = 0; c < 128; ++c) { float t = vbuf[c]; vbuf[c] = run; run += t; }
  #pragma unroll
  for (int c = 0; c < 128; ++c) SlocT[base + (size_t)c * 16384] = f2b(vbuf[c]);
}

// ---- k_zprefix: in-place exclusive prefix of zloc over chunks (f32) --------
__global__ __launch_bounds__(64) void k_zprefix(float* __restrict__ zloc) {
  int b = blockIdx.x >> 2, ig = blockIdx.x & 3;
  int i = ig * 64 + threadIdx.x;
  size_t base = (size_t)b * 32768 + i;
  float vbuf[128];
  #pragma unroll
  for (int c = 0; c < 128; ++c) vbuf[c] = zloc[base + (size_t)c * 256];
  float run = 0.f;
  #pragma unroll
  for (int c = 0; c < 128; ++c) { float t = vbuf[c]; vbuf[c] = run; run += t; }
  #pragma unroll
  for (int c = 0; c < 128; ++c) zloc[base + (size_t)c * 256] = vbuf[c];
}

// ---- k_out (MFMA): out[t] = (phiQ@Sp + tril(A)@V) / (phiQ.zp + rowsum + eps)
// 1024 blocks x 4 waves; wave w owns m-tile (rows m0=w*16 .. +15).
//   mm1: A = phiQ @ phiK^T (K=256), triangular (n0 <= w only), masked in-reg,
//        rowsum den-partials, bf16 A -> wave-private LDS rows.
//   mm2: out1 = phiQ @ Sp   (K=256), b-frags = SpT LDS rows.
//   mm3: out2 = trilA @ V   (K=64),  V split hi+lo bf16.
// LDS 61440 B -> 2 blocks/CU; waves_per_eu(1,2) (spill tripwire R5-R11).
__global__ __launch_bounds__(256)
__attribute__((amdgpu_waves_per_eu(1, 2))) void k_out(
    const bf16* __restrict__ phiQ, const bf16* __restrict__ phiK,
    const void* __restrict__ v, const bf16* __restrict__ SlocT,
    const float* __restrict__ zloc, void* __restrict__ outp,
    const int* __restrict__ flag) {
  __shared__ short spT[64 * 264];   // SpT[d][i], pad 8     33792 B
  __shared__ short vTh[64 * 72];    // V^T hi bf16           9216 B
  __shared__ short vTl[64 * 72];    // V^T lo bf16           9216 B
  __shared__ short aT[64 * 72];     // masked A[t][tau]      9216 B

  int isf32 = *flag;
  int chunk = blockIdx.x;
  size_t tok0 = (size_t)chunk * 64;
  int tid = threadIdx.x;
  int lane = tid & 63;
  int li = lane & 15;
  int quad = lane >> 4;
  int w = __builtin_amdgcn_readfirstlane(tid >> 6);  // wave id = m-tile
  int m0 = w * 16;

  // ---- stage SpT: straight 16B copy of this chunk's exclusive-prefix S^T ---
  {
    const short* src = (const short*)SlocT + (size_t)chunk * 16384;
    #pragma unroll
    for (int it = 0; it < 8; ++it) {
      int e = it * 256 + tid;
      int d = e >> 5, seg = e & 31;
      *reinterpret_cast<short8*>(&spT[d * 264 + seg * 8]) =
          *reinterpret_cast<const short8*>(src + d * 256 + seg * 8);
    }
  }
  // ---- stage V^T split hi/lo (coalesced f32 reads; lo==0 for bf16 input) ---
  #pragma unroll
  for (int it = 0; it < 16; ++it) {
    int e = it * 256 + tid;
    int tau = e >> 6, d = e & 63;
    float vv = ldin(v, tok0 * 64 + e, isf32);
    bf16 h = f2b(vv);
    bf16 l = f2b(vv - b2f(h));
    vTh[d * 72 + tau] = *reinterpret_cast<short*>(&h);
    vTl[d * 72 + tau] = *reinterpret_cast<short*>(&l);
  }
  // ---- zero own above-diagonal A region (rows wave-private: no race) -------
  {
    shortx4 z4 = {0, 0, 0, 0};
    int row = m0 + li;
    for (int c = (w + 1) * 16 + quad * 4; c < 64; c += 16)
      *reinterpret_cast<shortx4*>(&aT[row * 72 + c]) = z4;
  }

  // ---- a1-frags: phiQ rows of this m-tile (L2-hot; reused mm1+mm2) ---------
  const short* pqf = (const short*)phiQ + (tok0 + m0 + li) * 256 + quad * 8;
  short8 a1[8];
  #pragma unroll
  for (int kk = 0; kk < 8; ++kk)
    a1[kk] = *reinterpret_cast<const short8*>(pqf + kk * 32);

  // ---- mm1: A tiles, n0 <= w only (tiles above diagonal are all-masked) ----
  floatx4 c1[4];
  #pragma unroll
  for (int n0 = 0; n0 < 4; ++n0) c1[n0] = (floatx4){0.f, 0.f, 0.f, 0.f};
  const short* pkb = (const short*)phiK + tok0 * 256;
  #pragma unroll
  for (int n0 = 0; n0 < 4; ++n0) {
    if (n0 <= w) {
      const short* bp = pkb + (size_t)(n0 * 16 + li) * 256 + quad * 8;
      floatx4 acc = c1[n0];
      #pragma unroll
      for (int kk = 0; kk < 8; ++kk) {
        short8 b = *reinterpret_cast<const short8*>(bp + kk * 32);
        acc = __builtin_amdgcn_mfma_f32_16x16x32_bf16(a1[kk], b, acc, 0, 0, 0);
      }
      c1[n0] = acc;
    }
  }

  // ---- tril mask + den rowsum partials + write bf16 A to own LDS rows ------
  float dpart[4] = {0.f, 0.f, 0.f, 0.f};
  #pragma unroll
  for (int n0 = 0; n0 < 4; ++n0) {
    if (n0 <= w) {
      int tau = n0 * 16 + li;
      #pragma unroll
      for (int r = 0; r < 4; ++r) {
        int t = m0 + quad * 4 + r;
        float val = (tau <= t) ? c1[n0][r] : 0.f;
        dpart[r] += val;
        bf16 hh = f2b(val);
        aT[t * 72 + tau] = *reinterpret_cast<short*>(&hh);
      }
    }
  }

  __syncthreads();   // spT/vTh/vTl ready (aT is wave-private: own rows only)

  // ---- mm2 (phiQ @ Sp) + mm3 (trilA @ Vhi + trilA @ Vlo), shared acc -------
  floatx4 o[4];
  #pragma unroll
  for (int n0 = 0; n0 < 4; ++n0) o[n0] = (floatx4){0.f, 0.f, 0.f, 0.f};

  const short* arow = &aT[(m0 + li) * 72 + quad * 8];
  short8 a3_0 = *reinterpret_cast<const short8*>(arow);
  short8 a3_1 = *reinterpret_cast<const short8*>(arow + 32);

  #pragma unroll
  for (int n0 = 0; n0 < 4; ++n0) {
    floatx4 acc = o[n0];
    const short* sp = &spT[(n0 * 16 + li) * 264 + quad * 8];
    #pragma unroll
    for (int kk = 0; kk < 8; ++kk) {
      short8 b = *reinterpret_cast<const short8*>(sp + kk * 32);
      acc = __builtin_amdgcn_mfma_f32_16x16x32_bf16(a1[kk], b, acc, 0, 0, 0);
    }
    const short* vph = &vTh[(n0 * 16 + li) * 72 + quad * 8];
    const short* vpl = &vTl[(n0 * 16 + li) * 72 + quad * 8];
    short8 bh0 = *reinterpret_cast<const short8*>(vph);
    short8 bh1 = *reinterpret_cast<const short8*>(vph + 32);
    short8 bl0 = *reinterpret_cast<const short8*>(vpl);
    short8 bl1 = *reinterpret_cast<const short8*>(vpl + 32);
    acc = __builtin_amdgcn_mfma_f32_16x16x32_bf16(a3_0, bh0, acc, 0, 0, 0);
    acc = __builtin_amdgcn_mfma_f32_16x16x32_bf16(a3_1, bh1, acc, 0, 0, 0);
    acc = __builtin_amdgcn_mfma_f32_16x16x32_bf16(a3_0, bl0, acc, 0, 0, 0);
    acc = __builtin_amdgcn_mfma_f32_16x16x32_bf16(a3_1, bl1, acc, 0, 0, 0);
    o[n0] = acc;
  }

  // ---- den: dpart += pq . zp  (lane li covers i in [li*16, li*16+16)) ------
  {
    const floatx4* zp4 =
        reinterpret_cast<const floatx4*>(zloc + (size_t)chunk * 256 + li * 16);
    floatx4 z0 = zp4[0], z1 = zp4[1], z2 = zp4[2], z3 = zp4[3];
    #pragma unroll
    for (int r = 0; r < 4; ++r) {
      const short* pqr =
          (const short*)phiQ + (tok0 + m0 + quad * 4 + r) * 256 + li * 16;
      short8 p0 = *reinterpret_cast<const short8*>(pqr);
      short8 p1 = *reinterpret_cast<const short8*>(pqr + 8);
      float s = dpart[r];
      #pragma unroll
      for (int j = 0; j < 4; ++j) s += bflo((unsigned short)p0[j]) * z0[j];
      #pragma unroll
      for (int j = 0; j < 4; ++j) s += bflo((unsigned short)p0[4 + j]) * z1[j];
      #pragma unroll
      for (int j = 0; j < 4; ++j) s += bflo((unsigned short)p1[j]) * z2[j];
      #pragma unroll
      for (int j = 0; j < 4; ++j) s += bflo((unsigned short)p1[4 + j]) * z3[j];
      dpart[r] = s;
    }
  }
  // butterfly over the quad's 16 lanes: every lane gets full den for its rows
  #pragma unroll
  for (int mask = 1; mask < 16; mask <<= 1) {
    #pragma unroll
    for (int r = 0; r < 4; ++r) dpart[r] += __shfl_xor(dpart[r], mask, 64);
  }

  // ---- epilogue: out[t][d] = (out1+out2) / (den + eps) ---------------------
  #pragma unroll
  for (int r = 0; r < 4; ++r) {
    float rd = 1.f / (dpart[r] + 1e-6f);
    size_t ob = (tok0 + m0 + quad * 4 + r) * 64 + li;
    if (isf32) {
      float* op = (float*)outp + ob;
      #pragma unroll
      for (int n0 = 0; n0 < 4; ++n0) op[n0 * 16] = o[n0][r] * rd;
    } else {
      bf16* op = (bf16*)outp + ob;
      #pragma unroll
      for (int n0 = 0; n0 < 4; ++n0) op[n0 * 16] = f2b(o[n0][r] * rd);
    }
  }
}

extern "C" void kernel_launch(void* const* d_in, const int* in_sizes, int n_in,
                              void* d_out, int out_size, void* d_ws, size_t ws_size,
                              hipStream_t stream) {
  (void)in_sizes; (void)n_in; (void)out_size;
  if (ws_size < NEED_WS_BYTES) return;   // diagnostic guard

  const void* q = d_in[0];
  const void* k = d_in[1];
  const void* v = d_in[2];
  const void* omega = d_in[3];

  int*   flag = (int*)d_ws;
  float* wsf  = (float*)d_ws + 64;       // data starts 256 B in
  bf16*  omb  = (bf16*)wsf;              // 16384 bf16
  float* zloc = wsf + 131072;            // 1024*256 f32
  bf16*  Sloc = (bf16*)(wsf + 393216);   // 1024*256*64 bf16 (TRANSPOSED [d][i])
  bf16*  phiQ = (bf16*)(wsf + 8781824);  // 65536*256 bf16
  bf16*  phiK = (bf16*)(wsf + 17170432); // 65536*256 bf16

  k_detect<<<1, 256, 0, stream>>>(q, flag);
  k_omega<<<64, 256, 0, stream>>>(omega, omb, flag);
  k_phi<<<dim3(1024, 2), 256, 0, stream>>>(q, k, omb, phiQ, phiK, flag);
  k_slocal<<<1024, 256, 0, stream>>>(phiK, v, Sloc, zloc, flag);
  k_sprefix<<<2048, 64, 0, stream>>>(Sloc);
  k_zprefix<<<32, 64, 0, stream>>>(zloc);
  k_out<<<1024, 256, 0, stream>>>(phiQ, phiK, v, Sloc, zloc, d_out, flag);
}